// Round 9
// baseline (218.815 us; speedup 1.0000x reference)
//
#include <hip/hip_runtime.h>

// ---------------------------------------------------------------------------
// SpectralMamba fused kernel (MI355X / gfx950) — R9: straight-line 32-row
// tile, U/XC LDS union -> 34.9 KB -> 3 blocks/CU under a 128 KB pool.
//
// Register discipline (R5-R8): straight-line body only (loop back-edges spill);
// __launch_bounds__(512,arg2) budgets VGPR ~= 256/arg2 -> use arg2=3 (~84) to
// hold xc_p (+16 regs) without the 64-cap cliff.
// xc*sz folded to pr regs post-GEMM1: phase 4 loses its LDS read and only 16
// regs persist past phase 2.5.
// ---------------------------------------------------------------------------

typedef _Float16 f16x8 __attribute__((ext_vector_type(8)));
typedef _Float16 f16x2 __attribute__((ext_vector_type(2)));
typedef __fp16 fp16x2b __attribute__((ext_vector_type(2)));   // builtin return type
typedef float f32x4 __attribute__((ext_vector_type(4)));
typedef float f32x2 __attribute__((ext_vector_type(2)));      // native vec for nontemporal

#define MFMA16(a,b,c) __builtin_amdgcn_mfma_f32_16x16x32_f16((a),(b),(c),0,0,0)

// workspace layout (bytes): packs are [k/8][outcol][k%8] f16 = W[k][outcol]
#define WPIN_OFF   0u        // 32k8 x 1024 x 8 f16 = 512 KB (xi half pre-scaled by conv_w[:,3])
#define WPOUT_OFF  524288u   // 64k8 x 256  x 8     = 256 KB
#define WPXP_OFF   786432u   // 64k8 x 48   x 8     = 48 KB
#define WPDT_OFF   835584u   // 4k8  x 512  x 8     = 32 KB (k8>=2 zero pad)

// LDS layout (bytes) — 32-row tile, U union'd into XC's first half
#define XC_OFF    0          // xc/y pack: [64 j8][32 m][8] f16 = 32768
#define U_OFF     0          // u pack:  [32 k8][32 m][8] f16 = 16384 (phases 1-2 only)
#define DTP_OFF   32768      // dt pack: [4 k8][32 m][8] f16 = 2048 (k8>=2 zeros)
#define BC_OFF    34816      // bc: [32] f32 = 128
#define LDS_BYTES 34944

__device__ __forceinline__ unsigned short f16bits(float f) {
  union { _Float16 h; unsigned short u; } c; c.h = (_Float16)f; return c.u;
}
__device__ __forceinline__ unsigned pk2(float a, float b) {
  union { fp16x2b h; unsigned u; } c;
  c.h = __builtin_amdgcn_cvt_pkrtz(a, b);
  return c.u;
}
__device__ __forceinline__ f16x2 upk(unsigned u) {
  union { unsigned u; f16x2 h; } c; c.u = u; return c.h;
}
__device__ __forceinline__ unsigned pkmul(unsigned a, unsigned b) {
  union { f16x2 h; unsigned u; } c; c.h = upk(a) * upk(b);   // v_pk_mul_f16
  return c.u;
}
__device__ __forceinline__ float siluf(float t) {
  return t * __builtin_amdgcn_rcpf(1.f + __expf(-t));
}
__device__ __forceinline__ float softplusf(float t) {
  return fmaxf(t, 0.f) + __logf(1.f + __expf(-fabsf(t)));
}

// pack fp32 [K][N] weight -> f16 fragment layout [KB][N][8], zero-pad k>=K
__global__ void pack_w_kernel(const float* __restrict__ src,
                              unsigned short* __restrict__ dst,
                              int K, int N, int KB) {
  int t = blockIdx.x * 256 + threadIdx.x;
  if (t >= KB * N * 8) return;
  int ke = t & 7;
  int n  = (t >> 3) % N;
  int kb = t / (N * 8);
  int k  = kb * 8 + ke;
  float v = (k < K) ? src[k * N + n] : 0.f;
  dst[t] = f16bits(v);
}

// pack W_in with conv_w[:,3] folded into the xi half (cols 0..511)
__global__ void pack_win_kernel(const float* __restrict__ W_in,
                                const float* __restrict__ conv_w,
                                unsigned short* __restrict__ dst) {
  int t = blockIdx.x * 256 + threadIdx.x;   // 32*1024*8 = 262144 total
  int ke = t & 7;
  int n  = (t >> 3) & 1023;
  int kb = t >> 13;
  float v = W_in[(kb * 8 + ke) * 1024 + n];
  if (n < 512) v *= conv_w[n * 4 + 3];
  dst[t] = f16bits(v);
}

__global__ __launch_bounds__(512, 3) void mamba_fused_kernel(
    const float* __restrict__ x,
    const float* __restrict__ conv_b,
    const float* __restrict__ b_dt,
    const float* __restrict__ Dvec,
    float* __restrict__ out,
    const char* __restrict__ ws)
{
  __shared__ __align__(16) char smem[LDS_BYTES];

  const int tid  = threadIdx.x;
  const int wv   = tid >> 6;     // wave 0..7
  const int l    = tid & 63;
  const int lrow = l & 15;
  const int lhi  = l >> 4;

  const int wg   = blockIdx.x;            // 0..4095
  const int w0   = (wg & 3) << 5;         // w offset 0/32/64/96
  const int hb   = wg >> 2;
  const int h    = hb & 127;
  const int bidx = hb >> 7;

  const f16x8* wp_in  = (const f16x8*)(ws + WPIN_OFF);
  const f16x8* wp_out = (const f16x8*)(ws + WPOUT_OFF);
  const f16x8* wp_xp  = (const f16x8*)(ws + WPXP_OFF);
  const f16x8* wp_dt  = (const f16x8*)(ws + WPDT_OFF);

  // zero dt-pack k8=2,3 (K padding for GEMM3); first read in phase 4
  if (tid < 64) {
    f32x4 z4 = {0.f, 0.f, 0.f, 0.f};
    *(f32x4*)(smem + DTP_OFF + 1024 + tid * 16) = z4;
  }

  const int xoff0 = (bidx * 256 * 128 + h) * 128 + w0;   // fits int32

  // -------- phase 1: load u tile (32 rows x 256 ch) -> U pack --------
  {
    const float* xb = x + xoff0;
    const int m2 = (tid & 15) * 2;   // rows m2, m2+1
    const int k8 = tid >> 4;         // channel group 0..31
    f32x2 v[8];
    #pragma unroll
    for (int j = 0; j < 8; ++j)
      v[j] = __builtin_nontemporal_load(
               (const f32x2*)(xb + (k8 * 8 + j) * 16384 + m2));
    uint4 pe, po;
    pe.x = pk2(v[0].x, v[1].x); pe.y = pk2(v[2].x, v[3].x);
    pe.z = pk2(v[4].x, v[5].x); pe.w = pk2(v[6].x, v[7].x);
    po.x = pk2(v[0].y, v[1].y); po.y = pk2(v[2].y, v[3].y);
    po.z = pk2(v[4].y, v[5].y); po.w = pk2(v[6].y, v[7].y);
    char* ub = smem + U_OFF + (k8 * 32 + m2) * 16;
    *(uint4*)ub = pe;
    *(uint4*)(ub + 16) = po;
  }
  __syncthreads();

  unsigned xc_p[4][2][2];   // silu(xi*cw+cb) f16 pairs: [q][rt][p]
  unsigned sz_p[4][2][2];   // silu(z)

  // -------- phase 2: GEMM1 xz^T = W_in^T @ u^T; xc,sz -> regs --------
  #pragma unroll
  for (int hf = 0; hf < 2; ++hf) {           // 0: xi (conv folded), 1: z
    const int cb = hf * 512 + wv * 64;
    #pragma unroll
    for (int qp = 0; qp < 2; ++qp) {
      f32x4 acc[2][2];
      #pragma unroll
      for (int q2 = 0; q2 < 2; ++q2) {
        if (hf == 0) {
          f32x4 cb4 = *(const f32x4*)(conv_b + cb + (qp * 2 + q2) * 16 + lhi * 4);
          acc[q2][0] = cb4; acc[q2][1] = cb4;
        } else {
          f32x4 z4 = {0.f, 0.f, 0.f, 0.f};
          acc[q2][0] = z4; acc[q2][1] = z4;
        }
      }
      __builtin_amdgcn_s_setprio(1);
      #pragma unroll
      for (int s = 0; s < 8; ++s) {
        f16x8 b[2];
        #pragma unroll
        for (int rt = 0; rt < 2; ++rt)
          b[rt] = *(const f16x8*)(smem + U_OFF + ((s * 4 + lhi) * 32 + rt * 16 + lrow) * 16);
        f16x8 a[2];
        #pragma unroll
        for (int q2 = 0; q2 < 2; ++q2)
          a[q2] = wp_in[(s * 4 + lhi) * 1024 + cb + (qp * 2 + q2) * 16 + lrow];
        #pragma unroll
        for (int q2 = 0; q2 < 2; ++q2)
          #pragma unroll
          for (int rt = 0; rt < 2; ++rt)
            acc[q2][rt] = MFMA16(a[q2], b[rt], acc[q2][rt]);
      }
      __builtin_amdgcn_s_setprio(0);
      #pragma unroll
      for (int q2 = 0; q2 < 2; ++q2) {
        const int q = qp * 2 + q2;
        #pragma unroll
        for (int rt = 0; rt < 2; ++rt) {
          float s0 = siluf(acc[q2][rt][0]);
          float s1 = siluf(acc[q2][rt][1]);
          float s2 = siluf(acc[q2][rt][2]);
          float s3 = siluf(acc[q2][rt][3]);
          if (hf == 0) {
            xc_p[q][rt][0] = pk2(s0, s1);
            xc_p[q][rt][1] = pk2(s2, s3);
          } else {
            sz_p[q][rt][0] = pk2(s0, s1);
            sz_p[q][rt][1] = pk2(s2, s3);
          }
        }
      }
    }
  }

  // pr = xc * sz (phase 4 needs only the product); computed before the
  // barrier so the VALU work overlaps other waves draining GEMM1.
  unsigned pr[4][2][2];
  #pragma unroll
  for (int q = 0; q < 4; ++q)
    #pragma unroll
    for (int rt = 0; rt < 2; ++rt)
      #pragma unroll
      for (int p = 0; p < 2; ++p)
        pr[q][rt][p] = pkmul(xc_p[q][rt][p], sz_p[q][rt][p]);

  __syncthreads();   // all GEMM1 reads of U done; XC region may be written

  // -------- phase 2.5: xc -> LDS pack [j/8][m][j%8] --------
  #pragma unroll
  for (int q = 0; q < 4; ++q) {
    const int j0 = wv * 64 + q * 16 + lhi * 4;
    char* base = smem + XC_OFF + ((j0 >> 3) * 32) * 16 + (j0 & 7) * 2;
    #pragma unroll
    for (int rt = 0; rt < 2; ++rt) {
      uint2 w2; w2.x = xc_p[q][rt][0]; w2.y = xc_p[q][rt][1];
      *(uint2*)(base + (rt * 16 + lrow) * 16) = w2;
    }
  }
  __syncthreads();

  // -------- phase 3: GEMM2 dbc^T = W_xproj^T @ xc^T --------
  // waves 0-1: Bm & Cm (mt=wv) + in-register bc; waves 2-3: dt (mt=wv-2)
  if (wv < 2) {
    const int mt = wv;
    f32x4 accB = {0.f,0.f,0.f,0.f}, accC = {0.f,0.f,0.f,0.f};
    #pragma unroll
    for (int s = 0; s < 16; ++s) {
      f16x8 bx = *(const f16x8*)(smem + XC_OFF + ((s * 4 + lhi) * 32 + mt * 16 + lrow) * 16);
      f16x8 aB = wp_xp[(s * 4 + lhi) * 48 + 16 + lrow];
      f16x8 aC = wp_xp[(s * 4 + lhi) * 48 + 32 + lrow];
      accB = MFMA16(aB, bx, accB);
      accC = MFMA16(aC, bx, accC);
    }
    float sbc = accB[0]*accC[0] + accB[1]*accC[1] + accB[2]*accC[2] + accB[3]*accC[3];
    sbc += __shfl_xor(sbc, 16);
    sbc += __shfl_xor(sbc, 32);
    if (lhi == 0)
      *(float*)(smem + BC_OFF + (mt * 16 + lrow) * 4) = sbc;
  } else if (wv < 4) {
    const int mt = wv - 2;
    f32x4 accD = {0.f,0.f,0.f,0.f};
    #pragma unroll
    for (int s = 0; s < 16; ++s) {
      f16x8 bx = *(const f16x8*)(smem + XC_OFF + ((s * 4 + lhi) * 32 + mt * 16 + lrow) * 16);
      f16x8 aD = wp_xp[(s * 4 + lhi) * 48 + lrow];
      accD = MFMA16(aD, bx, accD);
    }
    const int p0 = lhi * 4;
    uint2 w2; w2.x = pk2(accD[0], accD[1]); w2.y = pk2(accD[2], accD[3]);
    *(uint2*)(smem + DTP_OFF + ((p0 >> 3) * 32 + mt * 16 + lrow) * 16 + (p0 & 7) * 2) = w2;
  }
  __syncthreads();

  // -------- phase 4: GEMM3 delta + recombine y (in-place in XC) --------
  {
    f16x8 b3[2];
    #pragma unroll
    for (int rt = 0; rt < 2; ++rt)
      b3[rt] = *(const f16x8*)(smem + DTP_OFF + (lhi * 32 + rt * 16 + lrow) * 16);
    float bcr[2];
    #pragma unroll
    for (int rt = 0; rt < 2; ++rt)
      bcr[rt] = *(const float*)(smem + BC_OFF + (rt * 16 + lrow) * 4);
    #pragma unroll
    for (int q = 0; q < 4; ++q) {
      const int j0 = wv * 64 + q * 16 + lhi * 4;
      f32x4 bd = *(const f32x4*)(b_dt + j0);
      f32x4 dv = *(const f32x4*)(Dvec + j0);
      f16x8 a3 = wp_dt[lhi * 512 + wv * 64 + q * 16 + lrow];
      f32x4 acc3[2];
      #pragma unroll
      for (int rt = 0; rt < 2; ++rt)
        acc3[rt] = MFMA16(a3, b3[rt], bd);
      #pragma unroll
      for (int rt = 0; rt < 2; ++rt) {
        char* xaddr = smem + XC_OFF + ((j0 >> 3) * 32 + rt * 16 + lrow) * 16 + (j0 & 7) * 2;
        uint2 yw;
        #pragma unroll
        for (int p = 0; p < 2; ++p) {
          f16x2 prv = upk(pr[q][rt][p]);
          float d0 = softplusf(acc3[rt][2 * p]);
          float d1 = softplusf(acc3[rt][2 * p + 1]);
          float y0 = (d0 * bcr[rt] + dv[2 * p])     * (float)prv[0];
          float y1 = (d1 * bcr[rt] + dv[2 * p + 1]) * (float)prv[1];
          unsigned u = pk2(y0, y1);
          if (p == 0) yw.x = u; else yw.y = u;
        }
        *(uint2*)xaddr = yw;
      }
    }
  }
  __syncthreads();

  // -------- phase 5: GEMM4 out^T = W_out^T @ y^T --------
  {
    f32x4 acc4[2][2];
    #pragma unroll
    for (int c2 = 0; c2 < 2; ++c2)
      #pragma unroll
      for (int mt = 0; mt < 2; ++mt) {
        f32x4 z4 = {0.f, 0.f, 0.f, 0.f};
        acc4[c2][mt] = z4;
      }
    __builtin_amdgcn_s_setprio(1);
    #pragma unroll
    for (int s = 0; s < 16; ++s) {
      f16x8 by[2];
      #pragma unroll
      for (int mt = 0; mt < 2; ++mt)
        by[mt] = *(const f16x8*)(smem + XC_OFF + ((s * 4 + lhi) * 32 + mt * 16 + lrow) * 16);
      f16x8 aw[2];
      #pragma unroll
      for (int c2 = 0; c2 < 2; ++c2)
        aw[c2] = wp_out[(s * 4 + lhi) * 256 + wv * 32 + c2 * 16 + lrow];
      #pragma unroll
      for (int c2 = 0; c2 < 2; ++c2)
        #pragma unroll
        for (int mt = 0; mt < 2; ++mt)
          acc4[c2][mt] = MFMA16(aw[c2], by[mt], acc4[c2][mt]);
    }
    __builtin_amdgcn_s_setprio(0);
    // c = wv*32 + c2*16 + lhi*4 + i ; m = mt*16 + lrow
    const int obase = (bidx * 256 + wv * 32 + lhi * 4) * 16384 + h * 128 + w0 + lrow;
    #pragma unroll
    for (int c2 = 0; c2 < 2; ++c2)
      #pragma unroll
      for (int i = 0; i < 4; ++i)
        #pragma unroll
        for (int mt = 0; mt < 2; ++mt)
          __builtin_nontemporal_store(acc4[c2][mt][i],
              out + obase + (c2 * 16 + i) * 16384 + mt * 16);
  }
}

extern "C" void kernel_launch(void* const* d_in, const int* in_sizes, int n_in,
                              void* d_out, int out_size, void* d_ws, size_t ws_size,
                              hipStream_t stream) {
  const float* x       = (const float*)d_in[0];
  const float* W_in    = (const float*)d_in[1];
  const float* conv_w  = (const float*)d_in[2];
  const float* conv_b  = (const float*)d_in[3];
  const float* W_xproj = (const float*)d_in[4];
  const float* W_dt    = (const float*)d_in[5];
  const float* b_dt    = (const float*)d_in[6];
  // d_in[7] = A_log: unused by the reference's L=1 path
  const float* Dvec    = (const float*)d_in[8];
  const float* W_out   = (const float*)d_in[9];
  float* out = (float*)d_out;
  char* ws = (char*)d_ws;

  // pack weights to f16 fragment layout (once per launch, ~870 KB)
  pack_win_kernel<<<dim3(1024), dim3(256), 0, stream>>>(W_in, conv_w, (unsigned short*)(ws + WPIN_OFF));
  pack_w_kernel<<<dim3(512),  dim3(256), 0, stream>>>(W_out,   (unsigned short*)(ws + WPOUT_OFF), 512, 256, 64);
  pack_w_kernel<<<dim3(96),   dim3(256), 0, stream>>>(W_xproj, (unsigned short*)(ws + WPXP_OFF), 512, 48, 64);
  pack_w_kernel<<<dim3(64),   dim3(256), 0, stream>>>(W_dt,    (unsigned short*)(ws + WPDT_OFF), 16, 512, 4);

  // 4096 workgroups x 512 threads; one 32-row tile per block, no outer loop
  mamba_fused_kernel<<<dim3(4096), dim3(512), 0, stream>>>(
      x, conv_b, b_dt, Dvec, out, (const char*)ws);
}

// Round 10
// 202.193 us; speedup vs baseline: 1.0822x; 1.0822x over previous
//
#include <hip/hip_runtime.h>

// ---------------------------------------------------------------------------
// SpectralMamba fused kernel (MI355X / gfx950) — R10: R3 structure (64-row
// tile, 2048 blocks, proven 191 us) + GEMM1 LDS-read halving.
//
// GEMM1 restructured s-outer with 4 column-frags merged per row-half:
//   old: per (hf,qp): 8s x {4 b-reads, 2 a-reads, 8 MFMA}  -> 128 U-reads/wave
//   new: per (hf,rh): 8s x {2 b-reads, 4 a-reads, 8 MFMA}  ->  64 U-reads/wave
// U-tile LDS traffic halves (1 MB -> 512 KB per block); weight loads double
// but are L2-resident VMEM-pipe loads hidden under MFMA.
//
// Register discipline (R5-R9): straight-line body only; __launch_bounds__
// (512,4) -> 64-VGPR class, zero spill (watch FETCH_SIZE for regressions).
// Occupancy is pinned at 2 blocks/CU regardless of LDS (R8/R9 falsified).
// ---------------------------------------------------------------------------

typedef _Float16 f16x8 __attribute__((ext_vector_type(8)));
typedef _Float16 f16x2 __attribute__((ext_vector_type(2)));
typedef __fp16 fp16x2b __attribute__((ext_vector_type(2)));   // builtin return type
typedef float f32x4 __attribute__((ext_vector_type(4)));

#define MFMA16(a,b,c) __builtin_amdgcn_mfma_f32_16x16x32_f16((a),(b),(c),0,0,0)

// workspace layout (bytes): packs are [k/8][outcol][k%8] f16 = W[k][outcol]
#define WPIN_OFF   0u        // 32k8 x 1024 x 8 f16 = 512 KB (xi half pre-scaled by conv_w[:,3])
#define WPOUT_OFF  524288u   // 64k8 x 256  x 8     = 256 KB
#define WPXP_OFF   786432u   // 64k8 x 48   x 8     = 48 KB
#define WPDT_OFF   835584u   // 4k8  x 512  x 8     = 32 KB (k8>=2 zero pad)

// LDS layout (bytes). U region (phases 1-2) is union'd with XC (phases >=2.5).
#define U_OFF     0          // u pack:  [32 k8][64 m][8] f16 = 32 KB
#define XC_OFF    0          // xc/y pack: [64 j8][64 m][8] f16 = 64 KB
#define DTP_OFF   65536      // dt pack: [4 k8][64 m][8] f16 = 4 KB (k8>=2 zeros)
#define BC_OFF    69632      // bc: [64] f32
#define LDS_BYTES 69888

__device__ __forceinline__ unsigned short f16bits(float f) {
  union { _Float16 h; unsigned short u; } c; c.h = (_Float16)f; return c.u;
}
__device__ __forceinline__ unsigned pk2(float a, float b) {
  union { fp16x2b h; unsigned u; } c;
  c.h = __builtin_amdgcn_cvt_pkrtz(a, b);
  return c.u;
}
__device__ __forceinline__ f16x2 upk(unsigned u) {
  union { unsigned u; f16x2 h; } c; c.u = u; return c.h;
}
__device__ __forceinline__ float siluf(float t) {
  return t * __builtin_amdgcn_rcpf(1.f + __expf(-t));
}
__device__ __forceinline__ float softplusf(float t) {
  return fmaxf(t, 0.f) + __logf(1.f + __expf(-fabsf(t)));
}

// pack fp32 [K][N] weight -> f16 fragment layout [KB][N][8], zero-pad k>=K
__global__ void pack_w_kernel(const float* __restrict__ src,
                              unsigned short* __restrict__ dst,
                              int K, int N, int KB) {
  int t = blockIdx.x * 256 + threadIdx.x;
  if (t >= KB * N * 8) return;
  int ke = t & 7;
  int n  = (t >> 3) % N;
  int kb = t / (N * 8);
  int k  = kb * 8 + ke;
  float v = (k < K) ? src[k * N + n] : 0.f;
  dst[t] = f16bits(v);
}

// pack W_in with conv_w[:,3] folded into the xi half (cols 0..511)
__global__ void pack_win_kernel(const float* __restrict__ W_in,
                                const float* __restrict__ conv_w,
                                unsigned short* __restrict__ dst) {
  int t = blockIdx.x * 256 + threadIdx.x;   // 32*1024*8 = 262144 total
  int ke = t & 7;
  int n  = (t >> 3) & 1023;
  int kb = t >> 13;
  float v = W_in[(kb * 8 + ke) * 1024 + n];
  if (n < 512) v *= conv_w[n * 4 + 3];
  dst[t] = f16bits(v);
}

__global__ __launch_bounds__(512, 4) void mamba_fused_kernel(
    const float* __restrict__ x,
    const float* __restrict__ conv_b,
    const float* __restrict__ b_dt,
    const float* __restrict__ Dvec,
    float* __restrict__ out,
    const char* __restrict__ ws)
{
  __shared__ __align__(16) char smem[LDS_BYTES];

  const int tid  = threadIdx.x;
  const int wv   = tid >> 6;     // wave 0..7
  const int l    = tid & 63;
  const int lrow = l & 15;
  const int lhi  = l >> 4;

  const int wg   = blockIdx.x;
  const int w0   = (wg & 1) << 6;
  const int hb   = wg >> 1;
  const int h    = hb & 127;
  const int bidx = hb >> 7;

  const f16x8* wp_in  = (const f16x8*)(ws + WPIN_OFF);
  const f16x8* wp_out = (const f16x8*)(ws + WPOUT_OFF);
  const f16x8* wp_xp  = (const f16x8*)(ws + WPXP_OFF);
  const f16x8* wp_dt  = (const f16x8*)(ws + WPDT_OFF);

  // zero dt-pack k8=2,3 (K padding for GEMM3); first read in phase 4
  if (tid < 128) {
    f32x4 z4 = {0.f, 0.f, 0.f, 0.f};
    *(f32x4*)(smem + DTP_OFF + 2048 + tid * 16) = z4;
  }

  // ---------------- phase 1: load u tile -> LDS B-pack [c/8][m][c%8] -------
  {
    const float* xb = x + ((long)(bidx * 256) * 128 + h) * 128 + w0;
    #pragma unroll
    for (int i = 0; i < 4; ++i) {
      int cg = i * 8 + wv;             // channel group 0..31 (8 channels each)
      float f[8];
      #pragma unroll
      for (int j = 0; j < 8; ++j)
        f[j] = __builtin_nontemporal_load(xb + (long)(cg * 8 + j) * 16384 + l);
      uint4 pk;
      pk.x = pk2(f[0], f[1]); pk.y = pk2(f[2], f[3]);
      pk.z = pk2(f[4], f[5]); pk.w = pk2(f[6], f[7]);
      *(uint4*)(smem + U_OFF + (cg * 64 + l) * 16) = pk;
    }
  }
  __syncthreads();

  unsigned xc_p[4][4][2];   // xc f16 pairs: [q][rt][p]; j = wv*64+q*16+lhi*4+{2p,2p+1}, m = rt*16+lrow
  unsigned sz_p[4][4][2];   // silu(z), same layout

  // ---------------- phase 2: GEMM1 xz^T = W_in^T @ u^T ----------------
  // s-outer, 4 col-frags merged, rows split in halves (acc stays 32 f32).
  #pragma unroll
  for (int hf = 0; hf < 2; ++hf) {           // 0: xi cols (conv folded), 1: z cols
    const int cb = hf * 512 + wv * 64;
    #pragma unroll
    for (int rh = 0; rh < 2; ++rh) {         // row half: rt = rh*2 + r2
      f32x4 acc[4][2];
      #pragma unroll
      for (int q = 0; q < 4; ++q) {
        if (hf == 0) {
          f32x4 cb4 = *(const f32x4*)(conv_b + cb + q * 16 + lhi * 4);
          acc[q][0] = cb4; acc[q][1] = cb4;
        } else {
          f32x4 z4 = {0.f, 0.f, 0.f, 0.f};
          acc[q][0] = z4; acc[q][1] = z4;
        }
      }
      __builtin_amdgcn_s_setprio(1);
      #pragma unroll
      for (int s = 0; s < 8; ++s) {
        f16x8 b[2];
        #pragma unroll
        for (int r2 = 0; r2 < 2; ++r2)
          b[r2] = *(const f16x8*)(smem + U_OFF +
                    ((s * 4 + lhi) * 64 + (rh * 2 + r2) * 16 + lrow) * 16);
        f16x8 a[4];
        #pragma unroll
        for (int q = 0; q < 4; ++q)
          a[q] = wp_in[(s * 4 + lhi) * 1024 + cb + q * 16 + lrow];
        #pragma unroll
        for (int q = 0; q < 4; ++q)
          #pragma unroll
          for (int r2 = 0; r2 < 2; ++r2)
            acc[q][r2] = MFMA16(a[q], b[r2], acc[q][r2]);
      }
      __builtin_amdgcn_s_setprio(0);
      #pragma unroll
      for (int q = 0; q < 4; ++q) {
        #pragma unroll
        for (int r2 = 0; r2 < 2; ++r2) {
          const int rt = rh * 2 + r2;
          float s0 = siluf(acc[q][r2][0]);
          float s1 = siluf(acc[q][r2][1]);
          float s2 = siluf(acc[q][r2][2]);
          float s3 = siluf(acc[q][r2][3]);
          if (hf == 0) {
            xc_p[q][rt][0] = pk2(s0, s1); xc_p[q][rt][1] = pk2(s2, s3);
          } else {
            sz_p[q][rt][0] = pk2(s0, s1); sz_p[q][rt][1] = pk2(s2, s3);
          }
        }
      }
    }
  }
  __syncthreads();   // U dead; XC region may now be written

  // ---------------- phase 2.5: xc -> LDS pack [j/8][m][j%8] ----------------
  {
    #pragma unroll
    for (int q = 0; q < 4; ++q) {
      const int j0 = wv * 64 + q * 16 + lhi * 4;
      char* base = smem + XC_OFF + ((j0 >> 3) * 64) * 16 + (j0 & 7) * 2;
      #pragma unroll
      for (int rt = 0; rt < 4; ++rt) {
        uint2 w2; w2.x = xc_p[q][rt][0]; w2.y = xc_p[q][rt][1];
        *(uint2*)(base + (rt * 16 + lrow) * 16) = w2;
      }
    }
  }
  __syncthreads();

  // ---------------- phase 3: GEMM2 dbc^T = W_xproj^T @ xc^T ----------------
  // waves 0-3: Bm & Cm tiles (mt=wv) + in-register bc reduce
  // waves 4-7: dt tile (mt=wv-4) -> DTP pack
  {
    if (wv < 4) {
      const int mt = wv;
      f32x4 accB = {0.f,0.f,0.f,0.f}, accC = {0.f,0.f,0.f,0.f};
      #pragma unroll
      for (int s = 0; s < 16; ++s) {
        f16x8 bx = *(const f16x8*)(smem + XC_OFF + ((s * 4 + lhi) * 64 + mt * 16 + lrow) * 16);
        f16x8 aB = wp_xp[(s * 4 + lhi) * 48 + 16 + lrow];
        f16x8 aC = wp_xp[(s * 4 + lhi) * 48 + 32 + lrow];
        accB = MFMA16(aB, bx, accB);
        accC = MFMA16(aC, bx, accC);
      }
      float sbc = accB[0]*accC[0] + accB[1]*accC[1] + accB[2]*accC[2] + accB[3]*accC[3];
      sbc += __shfl_xor(sbc, 16);
      sbc += __shfl_xor(sbc, 32);
      if (lhi == 0)
        *(float*)(smem + BC_OFF + (mt * 16 + lrow) * 4) = sbc;
    } else {
      const int mt = wv - 4;
      f32x4 accD = {0.f,0.f,0.f,0.f};
      #pragma unroll
      for (int s = 0; s < 16; ++s) {
        f16x8 bx = *(const f16x8*)(smem + XC_OFF + ((s * 4 + lhi) * 64 + mt * 16 + lrow) * 16);
        f16x8 aD = wp_xp[(s * 4 + lhi) * 48 + lrow];
        accD = MFMA16(aD, bx, accD);
      }
      const int p0 = lhi * 4;
      uint2 w2; w2.x = pk2(accD[0], accD[1]); w2.y = pk2(accD[2], accD[3]);
      *(uint2*)(smem + DTP_OFF + ((p0 >> 3) * 64 + mt * 16 + lrow) * 16 + (p0 & 7) * 2) = w2;
    }
  }
  __syncthreads();

  // ---------------- phase 4: GEMM3 delta^T = W_dt^T @ dt^T + recombine y ---
  {
    const int cb0 = wv * 64;
    f16x8 b3[4];
    #pragma unroll
    for (int rt = 0; rt < 4; ++rt)
      b3[rt] = *(const f16x8*)(smem + DTP_OFF + (lhi * 64 + rt * 16 + lrow) * 16);
    float bcr[4];
    #pragma unroll
    for (int rt = 0; rt < 4; ++rt)
      bcr[rt] = *(const float*)(smem + BC_OFF + (rt * 16 + lrow) * 4);
    #pragma unroll
    for (int q = 0; q < 4; ++q) {
      const int j0 = cb0 + q * 16 + lhi * 4;
      f32x4 bd = *(const f32x4*)(b_dt + j0);
      f32x4 dv = *(const f32x4*)(Dvec + j0);
      f16x8 a3 = wp_dt[lhi * 512 + cb0 + q * 16 + lrow];
      f32x4 acc3[4];
      #pragma unroll
      for (int rt = 0; rt < 4; ++rt)
        acc3[rt] = MFMA16(a3, b3[rt], bd);
      char* xbase = smem + XC_OFF + ((j0 >> 3) * 64) * 16 + (j0 & 7) * 2;
      #pragma unroll
      for (int rt = 0; rt < 4; ++rt) {
        uint2 yw;
        #pragma unroll
        for (int p = 0; p < 2; ++p) {
          f16x2 xv = upk(xc_p[q][rt][p]);
          f16x2 zv = upk(sz_p[q][rt][p]);
          f16x2 pr = xv * zv;                       // v_pk_mul_f16
          float d0 = softplusf(acc3[rt][2 * p]);
          float d1 = softplusf(acc3[rt][2 * p + 1]);
          float y0 = (d0 * bcr[rt] + dv[2 * p])     * (float)pr[0];
          float y1 = (d1 * bcr[rt] + dv[2 * p + 1]) * (float)pr[1];
          unsigned u = pk2(y0, y1);
          if (p == 0) yw.x = u; else yw.y = u;
        }
        *(uint2*)(xbase + (rt * 16 + lrow) * 16) = yw;
      }
    }
  }
  __syncthreads();

  // ---------------- phase 5: GEMM4 out^T = W_out^T @ y^T ----------------
  {
    f32x4 acc4[2][4];
    #pragma unroll
    for (int c2 = 0; c2 < 2; ++c2)
      #pragma unroll
      for (int mt = 0; mt < 4; ++mt) {
        f32x4 z4 = {0.f, 0.f, 0.f, 0.f};
        acc4[c2][mt] = z4;
      }
    __builtin_amdgcn_s_setprio(1);
    #pragma unroll
    for (int s = 0; s < 16; ++s) {
      f16x8 by[4];
      #pragma unroll
      for (int mt = 0; mt < 4; ++mt)
        by[mt] = *(const f16x8*)(smem + XC_OFF + ((s * 4 + lhi) * 64 + mt * 16 + lrow) * 16);
      f16x8 aw[2];
      #pragma unroll
      for (int c2 = 0; c2 < 2; ++c2)
        aw[c2] = wp_out[(s * 4 + lhi) * 256 + wv * 32 + c2 * 16 + lrow];
      #pragma unroll
      for (int c2 = 0; c2 < 2; ++c2)
        #pragma unroll
        for (int mt = 0; mt < 4; ++mt)
          acc4[c2][mt] = MFMA16(aw[c2], by[mt], acc4[c2][mt]);
    }
    __builtin_amdgcn_s_setprio(0);
    // stores: ch = wv*32 + c2*16 + lhi*4 + i, m = mt*16 + lrow -> 64B-coalesced
    const long obase = (long)(bidx * 256 + wv * 32 + lhi * 4) * 16384 + h * 128 + w0 + lrow;
    #pragma unroll
    for (int c2 = 0; c2 < 2; ++c2)
      #pragma unroll
      for (int i = 0; i < 4; ++i)
        #pragma unroll
        for (int mt = 0; mt < 4; ++mt)
          __builtin_nontemporal_store(acc4[c2][mt][i],
              out + obase + (long)(c2 * 16 + i) * 16384 + mt * 16);
  }
}

extern "C" void kernel_launch(void* const* d_in, const int* in_sizes, int n_in,
                              void* d_out, int out_size, void* d_ws, size_t ws_size,
                              hipStream_t stream) {
  const float* x       = (const float*)d_in[0];
  const float* W_in    = (const float*)d_in[1];
  const float* conv_w  = (const float*)d_in[2];
  const float* conv_b  = (const float*)d_in[3];
  const float* W_xproj = (const float*)d_in[4];
  const float* W_dt    = (const float*)d_in[5];
  const float* b_dt    = (const float*)d_in[6];
  // d_in[7] = A_log: unused by the reference's L=1 path
  const float* Dvec    = (const float*)d_in[8];
  const float* W_out   = (const float*)d_in[9];
  float* out = (float*)d_out;
  char* ws = (char*)d_ws;

  // pack weights to f16 fragment layout (once per launch, ~870 KB)
  pack_win_kernel<<<dim3(1024), dim3(256), 0, stream>>>(W_in, conv_w, (unsigned short*)(ws + WPIN_OFF));
  pack_w_kernel<<<dim3(512),  dim3(256), 0, stream>>>(W_out,   (unsigned short*)(ws + WPOUT_OFF), 512, 256, 64);
  pack_w_kernel<<<dim3(96),   dim3(256), 0, stream>>>(W_xproj, (unsigned short*)(ws + WPXP_OFF), 512, 48, 64);
  pack_w_kernel<<<dim3(64),   dim3(256), 0, stream>>>(W_dt,    (unsigned short*)(ws + WPDT_OFF), 16, 512, 4);

  // 2048 workgroups x 512 threads; each handles 64 rows (one half w-line)
  mamba_fused_kernel<<<dim3(2048), dim3(512), 0, stream>>>(
      x, conv_b, b_dt, Dvec, out, (const char*)ws);
}